// Round 1
// 651.316 us; speedup vs baseline: 1.2464x; 1.2464x over previous
//
#include <hip/hip_runtime.h>

// ---------------- problem constants ----------------
#define DIMD 1024
#define BATCH 8
#define SEQ 4096
#define TCH 64                  // scan chunk length
#define NCH (SEQ / TCH)         // 64 chunks per sequence

typedef short short8 __attribute__((ext_vector_type(8)));
typedef unsigned short u16x8 __attribute__((ext_vector_type(8)));
typedef __bf16 bf16x8 __attribute__((ext_vector_type(8)));
typedef float f32x4 __attribute__((ext_vector_type(4)));

static __device__ __forceinline__ unsigned short f2bf(float f) {
    unsigned int u = __builtin_bit_cast(unsigned int, f);
    u += 0x7FFFu + ((u >> 16) & 1u);   // round-to-nearest-even
    return (unsigned short)(u >> 16);
}
static __device__ __forceinline__ float bf2f(unsigned short s) {
    return __builtin_bit_cast(float, ((unsigned int)s) << 16);
}

// ---------------- dtype detector (validated: detects fp32 here) ---------
__global__ void detect(const unsigned* __restrict__ xw, unsigned* __restrict__ flag) {
    if (threadIdx.x == 0 && blockIdx.x == 0) {
        int cnt = 0;
        for (int i = 0; i < 64; ++i) {
            unsigned lo = xw[i] & 0xFFFFu;
            unsigned e = (lo >> 7) & 0xFFu;
            if ((e >= 0x70u && e <= 0x8Fu) || lo == 0u) ++cnt;
        }
        *flag = (cnt >= 32) ? 1u : 0u;   // 1 = bf16 inputs, 0 = fp32 inputs
    }
}

// ---------------- small param vectors -> fp32 scratch ----------------
__global__ void cvt_small(const void* __restrict__ s0, const void* __restrict__ s1,
                          const void* __restrict__ s2, const void* __restrict__ s3,
                          const void* __restrict__ s4, const void* __restrict__ s5,
                          float* __restrict__ dst, const unsigned* __restrict__ flag) {
    const void* s;
    switch (blockIdx.y) {
        case 0: s = s0; break; case 1: s = s1; break; case 2: s = s2; break;
        case 3: s = s3; break; case 4: s = s4; break; default: s = s5; break;
    }
    int i = blockIdx.x * 256 + threadIdx.x;   // grid.x = 4 -> 0..1023
    float v = (*flag) ? bf2f(((const unsigned short*)s)[i]) : ((const float*)s)[i];
    dst[blockIdx.y * 1024 + i] = v;
}

// ---------------- weight matrices -> bf16 scratch (4x 2MiB contiguous) ----------
__global__ void cvt_W(const void* __restrict__ s0, const void* __restrict__ s1,
                      const void* __restrict__ s2, const void* __restrict__ s3,
                      unsigned short* __restrict__ dst, const unsigned* __restrict__ flag) {
    const void* s;
    switch (blockIdx.y) {
        case 0: s = s0; break; case 1: s = s1; break;
        case 2: s = s2; break; default: s = s3; break;
    }
    unsigned short* d = dst + (size_t)blockIdx.y * DIMD * DIMD;
    size_t i8 = (size_t)blockIdx.x * 256 + threadIdx.x;   // grid.x=512, 8 elts each
    if (*flag) {
        ((u16x8*)d)[i8] = ((const u16x8*)s)[i8];
    } else {
        const float4* s4 = (const float4*)s;
        float4 a = s4[i8 * 2], b = s4[i8 * 2 + 1];
        u16x8 o;
        o[0] = f2bf(a.x); o[1] = f2bf(a.y); o[2] = f2bf(a.z); o[3] = f2bf(a.w);
        o[4] = f2bf(b.x); o[5] = f2bf(b.y); o[6] = f2bf(b.z); o[7] = f2bf(b.w);
        ((u16x8*)d)[i8] = o;
    }
}

// ---------------- fused time-shift mix: writes mixk/mixv/mixr in one x pass -----
__global__ void prep3(const void* __restrict__ xb, size_t xoff,
                      const float* __restrict__ tmk, const float* __restrict__ tmv,
                      const float* __restrict__ tmr,
                      unsigned short* __restrict__ mix3, size_t mstride,
                      const unsigned* __restrict__ flag) {
    size_t i8 = (size_t)blockIdx.x * 256 + threadIdx.x;  // 8-element chunk index
    int d8 = (int)(i8 & 127);
    size_t row = i8 >> 7;
    int t = (int)(row & (SEQ - 1));
    float xv[8], xs[8];
    if (*flag) {
        const unsigned short* x = (const unsigned short*)xb + xoff;
        u16x8 a = ((const u16x8*)x)[i8];
#pragma unroll
        for (int j = 0; j < 8; ++j) xv[j] = bf2f(a[j]);
        if (t > 0) {
            u16x8 b = ((const u16x8*)x)[i8 - 128];
#pragma unroll
            for (int j = 0; j < 8; ++j) xs[j] = bf2f(b[j]);
        } else {
#pragma unroll
            for (int j = 0; j < 8; ++j) xs[j] = 0.f;
        }
    } else {
        const float* x = (const float*)xb + xoff;
        const float4* x4 = (const float4*)x;
        float4 a0 = x4[i8 * 2], a1 = x4[i8 * 2 + 1];
        xv[0]=a0.x; xv[1]=a0.y; xv[2]=a0.z; xv[3]=a0.w;
        xv[4]=a1.x; xv[5]=a1.y; xv[6]=a1.z; xv[7]=a1.w;
        if (t > 0) {
            float4 b0 = x4[i8 * 2 - 256], b1 = x4[i8 * 2 - 255];
            xs[0]=b0.x; xs[1]=b0.y; xs[2]=b0.z; xs[3]=b0.w;
            xs[4]=b1.x; xs[5]=b1.y; xs[6]=b1.z; xs[7]=b1.w;
        } else {
#pragma unroll
            for (int j = 0; j < 8; ++j) xs[j] = 0.f;
        }
    }
    const float4* k4 = (const float4*)tmk;
    const float4* v4 = (const float4*)tmv;
    const float4* r4 = (const float4*)tmr;
    float4 mk0 = k4[d8*2], mk1 = k4[d8*2+1];
    float4 mv0 = v4[d8*2], mv1 = v4[d8*2+1];
    float4 mr0 = r4[d8*2], mr1 = r4[d8*2+1];
    float mk[8] = {mk0.x,mk0.y,mk0.z,mk0.w, mk1.x,mk1.y,mk1.z,mk1.w};
    float mv[8] = {mv0.x,mv0.y,mv0.z,mv0.w, mv1.x,mv1.y,mv1.z,mv1.w};
    float mr[8] = {mr0.x,mr0.y,mr0.z,mr0.w, mr1.x,mr1.y,mr1.z,mr1.w};
    u16x8 ok, ov, orr;
#pragma unroll
    for (int j = 0; j < 8; ++j) {
        float dxy = xv[j] - xs[j];
        ok[j] = f2bf(xs[j] + mk[j] * dxy);
        ov[j] = f2bf(xs[j] + mv[j] * dxy);
        float r = xs[j] + mr[j] * dxy;
        orr[j] = f2bf(1.f / (1.f + __expf(-r)));
    }
    ((u16x8*)(mix3))[i8] = ok;
    ((u16x8*)(mix3 + mstride))[i8] = ov;
    ((u16x8*)(mix3 + 2 * mstride))[i8] = orr;
}

// ---------------- 256x256-tile 8-phase bf16 GEMM: C[M,N]=A[M,K]*W[N,K]^T --------
// K=N=1024, BK=64, 8 waves (2Mx4N), double-buffered 128KiB LDS, XOR-swizzled
// staging (conflict-free ds_read_b128), counted vmcnt (never 0 in main loop),
// setprio around MFMA clusters, XCD class swizzle, LDS-staged bf16 C epilogue.
//
// Stage-slot map per iteration (tiles E=2i->buf0 read p0-3, O=2i+1->buf1 read p4-7):
//   p0: O.A0   p1: O.A1   p2: E2.B0  p3: E2.B1 (+vmcnt(4) before trailing barrier)
//   p4: E2.A0  p5: E2.A1  p6: O2.B0  p7: O2.B1 (+vmcnt(4))
// Each stage targets a region whose last reads completed before a barrier that
// precedes the stage issue; vmcnt(4) allows exactly the 2 youngest half-tiles
// (4 loads/thread) to remain in flight across the barrier.

static __device__ __forceinline__ void stage_half(
    const unsigned short* __restrict__ g, unsigned short* l, int tid)
{
#pragma unroll
    for (int ld = 0; ld < 2; ++ld) {
        int c = ld * 512 + tid;            // 0..1023 chunks of 8 bf16 (16 B)
        int row = c >> 3;
        int jj = c & 7;
        int kA = (jj ^ (row & 7)) * 8;     // XOR swizzle on the GLOBAL k offset
        __builtin_amdgcn_global_load_lds(
            (const __attribute__((address_space(1))) void*)(g + (size_t)row * DIMD + kA),
            (__attribute__((address_space(3))) void*)(l + c * 8), 16, 0, 0);
    }
}

#define SA_L(buf, h) (lds + (buf) * 16384 + (h) * 8192)
#define SB_L(buf, h) (lds + 32768 + (buf) * 16384 + (h) * 8192)
#define STA(buf, h, t) stage_half(A + (row0 + (h) * 128) * DIMD + (t) * 64, SA_L(buf, h), tid)
#define STB(buf, h, t) stage_half(Wp + (col0 + (h) * 128) * DIMD + (t) * 64, SB_L(buf, h), tid)

#define PH(Q, BUF, STAGES, TAIL)                                                   \
    {                                                                              \
        const unsigned short* sAb = lds + (BUF) * 16384;                           \
        const unsigned short* sBb = lds + 32768 + (BUF) * 16384;                   \
        short8 af[2][2];                                                           \
        if ((Q) == 0) {                                                            \
            _Pragma("unroll") for (int nt = 0; nt < 4; ++nt)                       \
            _Pragma("unroll") for (int kh = 0; kh < 2; ++kh) {                     \
                int r = wn + nt * 16 + l15;                                        \
                int j = (kh * 4 + qd) ^ (r & 7);                                   \
                bfr[nt][kh] = *(const short8*)(sBb + r * 64 + j * 8);              \
            }                                                                      \
        }                                                                          \
        _Pragma("unroll") for (int m2 = 0; m2 < 2; ++m2)                           \
        _Pragma("unroll") for (int kh = 0; kh < 2; ++kh) {                         \
            int r = wm + ((Q) * 2 + m2) * 16 + l15;                                \
            int j = (kh * 4 + qd) ^ (r & 7);                                       \
            af[m2][kh] = *(const short8*)(sAb + r * 64 + j * 8);                   \
        }                                                                          \
        STAGES;                                                                    \
        asm volatile("s_barrier" ::: "memory");                                    \
        __builtin_amdgcn_s_setprio(1);                                             \
        _Pragma("unroll") for (int m2 = 0; m2 < 2; ++m2)                           \
        _Pragma("unroll") for (int nt = 0; nt < 4; ++nt)                           \
        _Pragma("unroll") for (int kh = 0; kh < 2; ++kh)                           \
            acc[(Q) * 2 + m2][nt] = __builtin_amdgcn_mfma_f32_16x16x32_bf16(       \
                __builtin_bit_cast(bf16x8, af[m2][kh]),                            \
                __builtin_bit_cast(bf16x8, bfr[nt][kh]),                           \
                acc[(Q) * 2 + m2][nt], 0, 0, 0);                                   \
        __builtin_amdgcn_s_setprio(0);                                             \
        TAIL;                                                                      \
        asm volatile("s_barrier" ::: "memory");                                    \
    }

__global__ __launch_bounds__(512, 2) void gemm_fused(
    const unsigned short* __restrict__ Aall,  // [nmat][M][1024] bf16
    const unsigned short* __restrict__ Wall,  // [nmat][1024][1024] bf16
    const float* __restrict__ biasf,          // [1024] fp32 or nullptr
    void* __restrict__ Cout, size_t coff,     // element offset into Cout
    int M, int nx, int force_bf16, const unsigned* __restrict__ flag)
{
    __shared__ unsigned short lds[65536];     // 128 KiB: A dbuf | B dbuf (also C tile)

    const int tid = threadIdx.x;
    const int lane = tid & 63;
    const int wv = tid >> 6;          // 0..7
    const int wm = (wv >> 2) * 128;   // 0 / 128
    const int wn = (wv & 3) * 64;     // 0..192
    const int l15 = lane & 15;
    const int qd = lane >> 4;

    const int id = blockIdx.x;
    const int cls = id & 7;           // XCD class
    const int sub = id >> 3;
    const int bx = sub % nx;          // col-inner: one XCD sweeps all cols of a row stripe
    const int by = cls + 8 * (sub / nx);
    const int which = bx >> 2;        // matrix select (nx=12 -> 3 mats, nx=4 -> 1)
    const unsigned short* A  = Aall + (size_t)which * M * DIMD;
    const unsigned short* Wp = Wall + (size_t)which * DIMD * DIMD;
    const size_t row0 = (size_t)by * 256;
    const size_t col0 = (size_t)(bx & 3) * 256;

    f32x4 acc[8][4];
#pragma unroll
    for (int i = 0; i < 8; ++i)
#pragma unroll
        for (int j = 0; j < 4; ++j)
            acc[i][j] = {0.f, 0.f, 0.f, 0.f};

    short8 bfr[4][2];

    // prologue: tile0 (buf0) complete + tile1.B halves (buf1); wait tile0 landed
    STB(0, 0, 0); STB(0, 1, 0);
    STA(0, 0, 0); STA(0, 1, 0);
    STB(1, 0, 1); STB(1, 1, 1);
    asm volatile("s_waitcnt vmcnt(4)" ::: "memory");
    asm volatile("s_barrier" ::: "memory");

    for (int it = 0; it < 8; ++it) {          // 2 K-tiles (BK=64) per iteration
        const int o  = 2 * it + 1;
        const int e2 = 2 * it + 2;
        const int o2 = 2 * it + 3;
        const bool pre = (it < 7);
        PH(0, 0, { STA(1, 0, o); }, {});
        PH(1, 0, { STA(1, 1, o); }, {});
        PH(2, 0, { if (pre) STB(0, 0, e2); }, {});
        PH(3, 0, { if (pre) STB(0, 1, e2); },
                 { if (pre) { asm volatile("s_waitcnt vmcnt(4)" ::: "memory"); }
                   else     { asm volatile("s_waitcnt vmcnt(0)" ::: "memory"); } });
        PH(0, 1, { if (pre) STA(0, 0, e2); }, {});
        PH(1, 1, { if (pre) STA(0, 1, e2); }, {});
        PH(2, 1, { if (pre) STB(1, 0, o2); }, {});
        PH(3, 1, { if (pre) STB(1, 1, o2); },
                 { if (pre) { asm volatile("s_waitcnt vmcnt(4)" ::: "memory"); } });
    }

    const bool wb16 = force_bf16 || (*flag != 0u);
    const size_t cbase = coff + (size_t)which * M * DIMD;
    if (wb16) {
        // stage C tile in LDS (chunk-XOR swizzled), then full-line coalesced stores
        unsigned short* sC = lds;     // 256x256 bf16 = 128 KiB, buffers are dead now
        float bvv[4];
#pragma unroll
        for (int nt = 0; nt < 4; ++nt)
            bvv[nt] = biasf ? biasf[col0 + wn + nt * 16 + l15] : 0.f;
#pragma unroll
        for (int mt = 0; mt < 8; ++mt)
#pragma unroll
        for (int nt = 0; nt < 4; ++nt)
#pragma unroll
        for (int i = 0; i < 4; ++i) {
            int row = wm + mt * 16 + qd * 4 + i;
            int col = wn + nt * 16 + l15;
            int j = col >> 3;
            int js = j ^ (((row >> 2) & 3) << 1);   // spread qd groups across banks
            sC[row * 256 + js * 8 + (col & 7)] = f2bf(acc[mt][nt][i] + bvv[nt]);
        }
        __syncthreads();
        unsigned short* Cb = (unsigned short*)Cout;
#pragma unroll
        for (int ch = 0; ch < 16; ++ch) {
            int c = ch * 512 + tid;   // 0..8191: (row, 16B col chunk)
            int row = c >> 5;
            int jj = c & 31;
            int js = jj ^ (((row >> 2) & 3) << 1);
            short8 vv = *(const short8*)(sC + row * 256 + js * 8);
            *(u16x8*)(Cb + cbase + (row0 + row) * DIMD + col0 + jj * 8) =
                __builtin_bit_cast(u16x8, vv);
        }
    } else {
        float* Cf = (float*)Cout;
#pragma unroll
        for (int nt = 0; nt < 4; ++nt) {
            size_t gc = col0 + wn + nt * 16 + l15;
            float bv = biasf ? biasf[gc] : 0.f;
#pragma unroll
            for (int mt = 0; mt < 8; ++mt)
#pragma unroll
            for (int i = 0; i < 4; ++i) {
                size_t gr = row0 + wm + mt * 16 + qd * 4 + i;
                Cf[cbase + gr * DIMD + gc] = acc[mt][nt][i] + bv;
            }
        }
    }
}

// ---------------- WKV scan, chunk-parallel 3-pass ----------------
__global__ void wkv_pass1(const unsigned short* __restrict__ kk,
                          const unsigned short* __restrict__ vv,
                          const float* __restrict__ uf, const float* __restrict__ wf,
                          float* __restrict__ aloc, float* __restrict__ bloc,
                          float* __restrict__ pp, int nchan)
{
    int e = blockIdx.x * 256 + threadIdx.x;
    int b = blockIdx.y, c = blockIdx.z;
    float uu = uf[e], ww = wf[e];
    size_t base = ((size_t)(b * SEQ + c * TCH)) * DIMD + e;
    float a = 0.f, bb = 0.f, P = 1.f;
    for (int t = 0; t < TCH; ++t) {
        float kt = bf2f(kk[base + (size_t)t * DIMD]);
        float vt = bf2f(vv[base + (size_t)t * DIMD]);
        float q = fmaxf(uu + kt, ww);
        float e1 = __expf(fminf(-ww - q, 60.f));
        float e2 = __expf(uu + kt - q);
        a = e1 * a + e2 * vt;
        bb = e1 * bb + e2;
        P *= e1;
    }
    P = fminf(fmaxf(P, 0.f), 1e30f);
    size_t si = (size_t)c * nchan + b * DIMD + e;
    aloc[si] = a; bloc[si] = bb; pp[si] = P;
}

__global__ void wkv_pass2(const float* __restrict__ aloc, const float* __restrict__ bloc,
                          const float* __restrict__ pp,
                          float* __restrict__ ain, float* __restrict__ bin, int nchan)
{
    int ch = blockIdx.x * 256 + threadIdx.x;
    float a = 0.f, b = 0.f;
    for (int c = 0; c < NCH; ++c) {
        size_t si = (size_t)c * nchan + ch;
        ain[si] = a; bin[si] = b;
        float P = pp[si];
        a = fmaf(P, a, aloc[si]);
        b = fmaf(P, b, bloc[si]);
    }
}

__global__ void wkv_pass3(const unsigned short* __restrict__ kk,
                          const unsigned short* __restrict__ vv,
                          const unsigned short* __restrict__ rr,
                          const float* __restrict__ uf, const float* __restrict__ wf,
                          const float* __restrict__ ain, const float* __restrict__ bin,
                          unsigned short* __restrict__ ao, int nchan)
{
    int e = blockIdx.x * 256 + threadIdx.x;
    int b = blockIdx.y, c = blockIdx.z;
    float uu = uf[e], ww = wf[e];
    size_t base = ((size_t)(b * SEQ + c * TCH)) * DIMD + e;
    size_t si = (size_t)c * nchan + b * DIMD + e;
    float a = ain[si], bb = bin[si];
    for (int t = 0; t < TCH; ++t) {
        size_t gi = base + (size_t)t * DIMD;
        float kt = bf2f(kk[gi]);
        float vt = bf2f(vv[gi]);
        float q = fmaxf(uu + kt, ww);
        float e1 = __expf(fminf(-ww - q, 60.f));
        float e2 = __expf(uu + kt - q);
        a = e1 * a + e2 * vt;
        bb = e1 * bb + e2;
        float wkv = a / fmaxf(bb, 1e-38f);
        float rv = bf2f(rr[gi]);
        ao[gi] = f2bf(wkv * rv);
    }
}

// ---------------- launch ----------------
extern "C" void kernel_launch(void* const* d_in, const int* in_sizes, int n_in,
                              void* d_out, int out_size, void* d_ws, size_t ws_size,
                              hipStream_t stream) {
    const void* x   = d_in[0];
    const void* u   = d_in[1];
    const void* w   = d_in[2];
    const void* tmk = d_in[3];
    const void* tmv = d_in[4];
    const void* tmr = d_in[5];
    const void* Wk  = d_in[6];
    const void* Wv  = d_in[7];
    const void* Wr  = d_in[8];
    const void* Wo  = d_in[9];
    const void* bo  = d_in[10];
    (void)in_sizes; (void)n_in; (void)out_size;

    const size_t MB = 1ull << 20;
    // host-constant grouping decision (same every call -> graph-safe)
    int nb;                                    // batches per group
    if      (ws_size >= 432 * MB) nb = 8;      // full batch, one pass
    else if (ws_size >= 124 * MB) nb = 2;      // 4 groups (validated: 149 MiB OK)
    else                          nb = 1;      // 8 groups (~66 MiB)
    const int ngroups = BATCH / nb;
    const size_t Mg = (size_t)nb * SEQ;        // tokens per group
    const int nchan = nb * DIMD;

    char* ws = (char*)d_ws;
    unsigned* flag = (unsigned*)(ws);
    float* smallf  = (float*)(ws + 64 * 1024);           // 6x1024 fp32
    unsigned short* Wb = (unsigned short*)(ws + 1 * MB); // 4x 2 MiB (Wk,Wv,Wr,Wo)
    unsigned short* mix3 = (unsigned short*)(ws + 16 * MB);
    size_t matB = Mg * DIMD * sizeof(unsigned short);    // bytes per [Mg,1024] bf16
    unsigned short* kvr = (unsigned short*)((char*)mix3 + 3 * matB);
    char* sc = (char*)kvr + 3 * matB;
    size_t scanB = (size_t)NCH * nchan * sizeof(float);
    float* aloc = (float*)(sc + 0 * scanB);
    float* bloc = (float*)(sc + 1 * scanB);
    float* pp   = (float*)(sc + 2 * scanB);
    float* ain  = (float*)(sc + 3 * scanB);
    float* bin  = (float*)(sc + 4 * scanB);

    float* uf   = smallf + 0 * 1024;
    float* wf   = smallf + 1 * 1024;
    float* tmkf = smallf + 2 * 1024;
    float* tmvf = smallf + 3 * 1024;
    float* tmrf = smallf + 4 * 1024;
    float* bof  = smallf + 5 * 1024;
    unsigned short* Wob = Wb + 3ull * DIMD * DIMD;

    detect<<<1, 64, 0, stream>>>((const unsigned*)x, flag);
    cvt_small<<<dim3(4, 6), 256, 0, stream>>>(u, w, tmk, tmv, tmr, bo, smallf, flag);
    cvt_W<<<dim3(512, 4), 256, 0, stream>>>(Wk, Wv, Wr, Wo, Wb, flag);

    const size_t mstride = Mg * DIMD;          // elements per matrix slot
    unsigned short* kk  = kvr;
    unsigned short* vvb = kvr + mstride;
    unsigned short* rrb = kvr + 2 * mstride;
    const int ny = (int)(Mg / 256);            // 256-row tiles (Mg multiple of 2048)
    dim3 gScan(DIMD / 256, nb, NCH);

    for (int g = 0; g < ngroups; ++g) {
        size_t xoff = (size_t)g * Mg * DIMD;   // element offset

        prep3<<<(int)(Mg * DIMD / 8 / 256), 256, 0, stream>>>(
            x, xoff, tmkf, tmvf, tmrf, mix3, mstride, flag);
        gemm_fused<<<12 * ny, 512, 0, stream>>>(
            mix3, Wb, nullptr, kvr, 0, (int)Mg, 12, 1, flag);

        wkv_pass1<<<gScan, 256, 0, stream>>>(kk, vvb, uf, wf, aloc, bloc, pp, nchan);
        wkv_pass2<<<nchan / 256, 256, 0, stream>>>(aloc, bloc, pp, ain, bin, nchan);
        wkv_pass3<<<gScan, 256, 0, stream>>>(kk, vvb, rrb, uf, wf, ain, bin, kk, nchan);

        gemm_fused<<<4 * ny, 512, 0, stream>>>(
            kk, Wob, bof, d_out, xoff, (int)Mg, 4, 0, flag);
    }
}